// Round 1
// baseline (856.376 us; speedup 1.0000x reference)
//
#include <hip/hip_runtime.h>
#include <stdint.h>

// Problem constants (fixed by reference: L=1024, B=8, D=2048)
#define L_SEQ 1024
#define BATCH 8
#define DIM   2048
#define GM    8192   // L*B
#define GN    6144   // 3*D
#define GK    2048   // D
#define SCALE_X 1.7320508075688772f  // sqrt(1 + 2*exp(0))

using bf16x8  = __attribute__((ext_vector_type(8))) __bf16;
using floatx4 = __attribute__((ext_vector_type(4))) float;

__device__ __forceinline__ unsigned short f2bf(float f) {
  unsigned u = __float_as_uint(f);
  u += 0x7FFFu + ((u >> 16) & 1u);   // round-to-nearest-even
  return (unsigned short)(u >> 16);
}
__device__ __forceinline__ float bf2f(unsigned short s) {
  return __uint_as_float(((unsigned)s) << 16);
}
__device__ __forceinline__ float sigmoidf_fast(float z) {
  return __builtin_amdgcn_rcpf(1.0f + __expf(-z));
}
// async global->LDS, 16B per lane. LDS dest must be wave-uniform base + lane*16.
__device__ __forceinline__ void async16(const unsigned short* g, unsigned short* l) {
  __builtin_amdgcn_global_load_lds(
      (__attribute__((address_space(1))) unsigned int*)g,
      (__attribute__((address_space(3))) unsigned int*)l,
      16, 0, 0);
}

// ---------------- cast x (fp32) -> A (bf16), same layout (GM x GK) -------------
__global__ __launch_bounds__(256) void cast_x_kernel(const float4* __restrict__ xin,
                                                     unsigned short* __restrict__ Aout) {
  const int n4 = (GM * GK) / 4;
  for (int i = blockIdx.x * blockDim.x + threadIdx.x; i < n4; i += gridDim.x * blockDim.x) {
    float4 v = xin[i];
    union { unsigned short s[4]; unsigned long long ll; } o;
    o.s[0] = f2bf(v.x); o.s[1] = f2bf(v.y); o.s[2] = f2bf(v.z); o.s[3] = f2bf(v.w);
    *(unsigned long long*)&Aout[(size_t)i * 4] = o.ll;
  }
}

// ------------- transpose-cast W (GK x GN fp32) -> Bt (GN x GK bf16) -------------
__global__ __launch_bounds__(256) void transpose_w_kernel(const float* __restrict__ W,
                                                          unsigned short* __restrict__ Bt) {
  __shared__ float tile[32][33];   // +1 pad: no bank conflicts
  const int tx = threadIdx.x & 31, ty = threadIdx.x >> 5;  // ty: 0..7
  const int n0 = blockIdx.x * 32;  // along GN
  const int k0 = blockIdx.y * 32;  // along GK
#pragma unroll
  for (int r = 0; r < 32; r += 8)
    tile[ty + r][tx] = W[(size_t)(k0 + ty + r) * GN + n0 + tx];
  __syncthreads();
#pragma unroll
  for (int r = 0; r < 32; r += 8)
    Bt[(size_t)(n0 + ty + r) * GK + k0 + tx] = f2bf(tile[tx][ty + r]);
}

// ---------------- GEMM: U(GM x GN, bf16) = A(GM x GK) * Bt(GN x GK)^T -----------
// 128x128 tile / block, 4 waves in 2x2, each wave 64x64 via 4x4 MFMA 16x16x32 tiles.
__global__ __launch_bounds__(256) void gemm_kernel(const unsigned short* __restrict__ A,
                                                   const unsigned short* __restrict__ Bt,
                                                   unsigned short* __restrict__ U) {
  __shared__ alignas(16) unsigned short As[128 * 32];  // [m][k], row = 64B
  __shared__ alignas(16) unsigned short Bs[128 * 32];  // [n][k]
  const int tid  = threadIdx.x;
  const int wave = tid >> 6, lane = tid & 63;
  const int quad = lane >> 4, lrow = lane & 15;
  const int wm = (wave >> 1) * 64, wn = (wave & 1) * 64;
  const int mBase = blockIdx.y * 128, nBase = blockIdx.x * 128;

  floatx4 acc[4][4] = {};

  // staging: flat byte offset o = issue*4096 + tid*16 ; row = o>>6 ; colbytes = o&63
  const int o0 = tid * 16;
  const int r0 = o0 >> 6;               // 0..63
  const int c0e = (o0 & 63) >> 1;       // bf16 col within 32
  const unsigned short* aG0 = A  + (size_t)(mBase + r0)      * GK + c0e;
  const unsigned short* aG1 = A  + (size_t)(mBase + r0 + 64) * GK + c0e;
  const unsigned short* bG0 = Bt + (size_t)(nBase + r0)      * GK + c0e;
  const unsigned short* bG1 = Bt + (size_t)(nBase + r0 + 64) * GK + c0e;
  unsigned short* asL0 = &As[o0 >> 1];
  unsigned short* asL1 = &As[(o0 >> 1) + 2048];
  unsigned short* bsL0 = &Bs[o0 >> 1];
  unsigned short* bsL1 = &Bs[(o0 >> 1) + 2048];

  for (int k0 = 0; k0 < GK; k0 += 32) {
    async16(aG0 + k0, asL0);
    async16(aG1 + k0, asL1);
    async16(bG0 + k0, bsL0);
    async16(bG1 + k0, bsL1);
    __syncthreads();   // drains vmcnt (global_load_lds) per compiler barrier semantics

    bf16x8 aF[4], bF[4];
#pragma unroll
    for (int t = 0; t < 4; ++t) {
      aF[t] = *(const bf16x8*)&As[(wm + t * 16 + lrow) * 32 + quad * 8];
      bF[t] = *(const bf16x8*)&Bs[(wn + t * 16 + lrow) * 32 + quad * 8];
    }
#pragma unroll
    for (int mt = 0; mt < 4; ++mt)
#pragma unroll
      for (int nt = 0; nt < 4; ++nt)
        acc[mt][nt] = __builtin_amdgcn_mfma_f32_16x16x32_bf16(aF[mt], bF[nt], acc[mt][nt], 0, 0, 0);
    __syncthreads();
  }

  // C/D layout (verified m89/m91): col = lane&15 (N), row = quad*4 + reg (M)
#pragma unroll
  for (int mt = 0; mt < 4; ++mt) {
    const int gm = mBase + wm + mt * 16 + quad * 4;
#pragma unroll
    for (int nt = 0; nt < 4; ++nt) {
      const int gn = nBase + wn + nt * 16 + lrow;
#pragma unroll
      for (int r = 0; r < 4; ++r)
        U[(size_t)(gm + r) * GN + gn] = f2bf(acc[mt][nt][r]);
    }
  }
}

// ---------------- SRU scan: sequential over L, one lane per (b,d) ---------------
// U rows are gm = l*B + b, row length GN=3D, interleaved (u0,u1,u2) at 3d..3d+2.
__global__ __launch_bounds__(64) void sru_scan_kernel(const unsigned short* __restrict__ U,
                                                      const float* __restrict__ x,
                                                      const float* __restrict__ c0,
                                                      const float* __restrict__ wc,
                                                      const float* __restrict__ bias,
                                                      float* __restrict__ out) {
  const int e = blockIdx.x * 64 + threadIdx.x;  // 0..16383
  const int b = e >> 11, d = e & 2047;
  const float vf = wc[d], vr = wc[DIM + d];
  const float bfv = bias[d], brv = bias[DIM + d];
  float c = c0[e];

  constexpr int    PF = 8;
  constexpr size_t US = (size_t)BATCH * GN;    // 49152 bf16 per l-step
  constexpr size_t XS = (size_t)BATCH * DIM;   // 16384 floats per l-step

  const unsigned short* uP = U + (size_t)b * GN + 3 * d;
  const float* xP = x + (size_t)b * DIM + d;
  float* hp = out + (size_t)b * DIM + d;

  float p0[PF], p1[PF], p2[PF], px[PF];
  {
    const unsigned short* up = uP;
    const float* xp = xP;
#pragma unroll
    for (int j = 0; j < PF; ++j) {
      p0[j] = bf2f(up[0]); p1[j] = bf2f(up[1]); p2[j] = bf2f(up[2]);
      px[j] = *xp;
      up += US; xp += XS;
    }
  }
  const unsigned short* upf = uP + (size_t)PF * US;
  const float* xpf = xP + (size_t)PF * XS;

  for (int l0 = 0; l0 < L_SEQ; l0 += PF) {
    const bool pf_ok = (l0 + 2 * PF) <= L_SEQ;  // uniform
#pragma unroll
    for (int j = 0; j < PF; ++j) {
      const float a0 = p0[j], a1 = p1[j], a2 = p2[j], ax = px[j];
      if (pf_ok) {
        p0[j] = bf2f(upf[0]); p1[j] = bf2f(upf[1]); p2[j] = bf2f(upf[2]);
        px[j] = *xpf;
      }
      upf += US; xpf += XS;
      const float f = sigmoidf_fast(a1 + vf * c + bfv);
      c = (c - a0) * f + a0;
      const float r = sigmoidf_fast(a2 + vr * c + brv);
      *hp = r * c + (1.0f - r) * ax * SCALE_X;
      hp += XS;
    }
  }
  out[(size_t)L_SEQ * BATCH * DIM + e] = c;  // c_last
}

// --------------------------------- launcher ------------------------------------
extern "C" void kernel_launch(void* const* d_in, const int* in_sizes, int n_in,
                              void* d_out, int out_size, void* d_ws, size_t ws_size,
                              hipStream_t stream) {
  const float* x    = (const float*)d_in[0];  // (L,B,D)
  const float* c0   = (const float*)d_in[1];  // (B,D)
  const float* W    = (const float*)d_in[2];  // (D, 3D)
  const float* wc   = (const float*)d_in[3];  // (2D,)
  const float* bias = (const float*)d_in[4];  // (2D,)
  float* out = (float*)d_out;                 // h (L*B*D) ++ c_last (B*D)

  char* ws = (char*)d_ws;
  unsigned short* A_bf  = (unsigned short*)(ws);              // GM*GK*2 = 32 MiB
  unsigned short* Bt_bf = (unsigned short*)(ws + 33554432);   // GN*GK*2 = 24 MiB
  unsigned short* U_bf  = (unsigned short*)(ws + 58720256);   // GM*GN*2 = 96 MiB

  cast_x_kernel<<<4096, 256, 0, stream>>>((const float4*)x, A_bf);
  transpose_w_kernel<<<dim3(GN / 32, GK / 32), 256, 0, stream>>>(W, Bt_bf);
  gemm_kernel<<<dim3(GN / 128, GM / 128), 256, 0, stream>>>(A_bf, Bt_bf, U_bf);
  sru_scan_kernel<<<256, 64, 0, stream>>>(U_bf, x, c0, wc, bias, out);
}